// Round 2
// baseline (464.232 us; speedup 1.0000x reference)
//
#include <hip/hip_runtime.h>
#include <hip/hip_bf16.h>

#define H 128

// ---------------- CSR build ----------------

__global__ void k_zero_i32(int* __restrict__ p, int n) {
    int i = blockIdx.x * blockDim.x + threadIdx.x;
    if (i < n) p[i] = 0;
}

__global__ void k_count(const int* __restrict__ dst, int* __restrict__ deg, int e) {
    int i = blockIdx.x * blockDim.x + threadIdx.x;
    if (i < e) atomicAdd(&deg[dst[i]], 1);
}

// block 1024: partial sums of deg chunks
__global__ __launch_bounds__(1024) void k_scan_partial(const int* __restrict__ deg,
                                                       int* __restrict__ partials, int n) {
    __shared__ int sm[1024];
    int t = threadIdx.x;
    int i = blockIdx.x * 1024 + t;
    sm[t] = (i < n) ? deg[i] : 0;
    __syncthreads();
    for (int s = 512; s > 0; s >>= 1) {
        if (t < s) sm[t] += sm[t + s];
        __syncthreads();
    }
    if (t == 0) partials[blockIdx.x] = sm[0];
}

// single block of 64: exclusive-scan partials in place (nb <= 64), write offsets[n]=total
__global__ __launch_bounds__(64) void k_scan_base(int* __restrict__ partials, int nb,
                                                  int* __restrict__ offsets, int n) {
    __shared__ int sm[64];
    int t = threadIdx.x;
    int v = (t < nb) ? partials[t] : 0;
    sm[t] = v;
    __syncthreads();
    for (int off = 1; off < 64; off <<= 1) {
        int x = 0;
        if (t >= off) x = sm[t - off];
        __syncthreads();
        if (t >= off) sm[t] += x;
        __syncthreads();
    }
    if (t < nb) partials[t] = sm[t] - v;  // exclusive
    if (t == 63) offsets[n] = sm[63];     // total
}

// per-chunk exclusive scan + base; also cursor copy + inv_deg
__global__ __launch_bounds__(1024) void k_scan_final(const int* __restrict__ deg,
                                                     const int* __restrict__ partials,
                                                     int* __restrict__ offsets,
                                                     int* __restrict__ cursor,
                                                     float* __restrict__ inv_deg, int n) {
    __shared__ int sm[1024];
    int t = threadIdx.x;
    int b = blockIdx.x;
    int i = b * 1024 + t;
    int v = (i < n) ? deg[i] : 0;
    sm[t] = v;
    __syncthreads();
    for (int off = 1; off < 1024; off <<= 1) {
        int x = 0;
        if (t >= off) x = sm[t - off];
        __syncthreads();
        if (t >= off) sm[t] += x;
        __syncthreads();
    }
    if (i < n) {
        int excl = partials[b] + sm[t] - v;
        offsets[i] = excl;
        cursor[i]  = excl;
        inv_deg[i] = 1.0f / fmaxf((float)v, 1.0f);
    }
}

__global__ void k_fill(const int* __restrict__ src, const int* __restrict__ dst,
                       int* __restrict__ cursor, int* __restrict__ csr, int e) {
    int i = blockIdx.x * blockDim.x + threadIdx.x;
    if (i < e) {
        int d = dst[i];
        int pos = atomicAdd(&cursor[d], 1);
        csr[pos] = src[i];
    }
}

// Wcat[l][k][j]: k<128 -> Wl[l][j][k], else Wr[l][j][k-128]
__global__ void k_wcat(const float* __restrict__ Wl, const float* __restrict__ Wr,
                       float* __restrict__ Wcat, int total) {
    int idx = blockIdx.x * blockDim.x + threadIdx.x;
    if (idx >= total) return;
    int l = idx / (256 * H);
    int rem = idx - l * 256 * H;
    int k = rem >> 7;
    int j = rem & 127;
    float v;
    if (k < H) v = Wl[(size_t)l * H * H + j * H + k];
    else       v = Wr[(size_t)l * H * H + j * H + (k - H)];
    Wcat[idx] = v;
}

// ---------------- per-layer kernels ----------------

// mean aggregation: 32 lanes per node (float4 each), 8 nodes per 256-thread block.
// Software-pipelined: prefetch next csr index + next feature vector before
// accumulating, so the per-edge dependent chain (idx load -> gather -> add)
// overlaps one L2 latency per iteration.
__global__ __launch_bounds__(256) void k_agg(const float* __restrict__ h,
                                             const int* __restrict__ csr,
                                             const int* __restrict__ offsets,
                                             const float* __restrict__ inv_deg,
                                             float* __restrict__ agg, int n) {
    int node = blockIdx.x * 8 + (threadIdx.x >> 5);
    int lane = threadIdx.x & 31;
    if (node >= n) return;
    int s = offsets[node];
    int eend = offsets[node + 1];
    const float4* hv = (const float4*)h;
    float4 acc = make_float4(0.f, 0.f, 0.f, 0.f);
    if (s < eend) {
        int src = csr[s];
        float4 v = hv[(size_t)src * 32 + lane];
        for (int p = s + 1; p < eend; ++p) {
            int nsrc = csr[p];                                // prefetch index
            float4 nv = hv[(size_t)nsrc * 32 + lane];          // issue next gather
            acc.x += v.x; acc.y += v.y; acc.z += v.z; acc.w += v.w;
            v = nv;
        }
        acc.x += v.x; acc.y += v.y; acc.z += v.z; acc.w += v.w;
    }
    float w = inv_deg[node];
    acc.x *= w; acc.y *= w; acc.z *= w; acc.w *= w;
    ((float4*)agg)[(size_t)node * 32 + lane] = acc;
}

// out[N][128] = [agg|h][N][256] @ Wcat[256][128] + bias, optional relu
// block 256 threads: tx=t&31 (cols tx+32c), ty=t>>5 (rows ty*8+r), tile 64 rows
__global__ __launch_bounds__(256) void k_gemm(const float* __restrict__ A0,   // agg
                                              const float* __restrict__ A1,   // h
                                              const float* __restrict__ Wc,   // [256][128]
                                              const float* __restrict__ bias, // [128]
                                              float* __restrict__ out, int n, int relu) {
    __shared__ float Asm[64][32];
    __shared__ float Wsm[32][H];
    int t = threadIdx.x;
    int tx = t & 31, ty = t >> 5;
    int row0 = blockIdx.x * 64;
    float acc[8][4];
#pragma unroll
    for (int r = 0; r < 8; ++r)
#pragma unroll
        for (int c = 0; c < 4; ++c) acc[r][c] = 0.f;

    for (int kc = 0; kc < 256; kc += 32) {
        const float* Asrc = (kc < H) ? A0 : A1;
        int kbase = kc & (H - 1);
        // A chunk: 64 rows x 32 k = 512 float4; coalesced idx = t + i*256
#pragma unroll
        for (int i = 0; i < 2; ++i) {
            int idx = t + i * 256;      // 0..511
            int r = idx >> 3;
            int q = idx & 7;
            int grow = row0 + r;
            float4 v = make_float4(0.f, 0.f, 0.f, 0.f);
            if (grow < n) v = *(const float4*)(Asrc + (size_t)grow * H + kbase + q * 4);
            *(float4*)(&Asm[r][q * 4]) = v;
        }
        // W chunk: 32 k x 128 j = 1024 float4
#pragma unroll
        for (int i = 0; i < 4; ++i) {
            int idx = t + i * 256;      // 0..1023
            int k = idx >> 5;
            int q = idx & 31;
            *(float4*)(&Wsm[k][q * 4]) = *(const float4*)(Wc + (size_t)(kc + k) * H + q * 4);
        }
        __syncthreads();
#pragma unroll
        for (int k = 0; k < 32; ++k) {
            float w0 = Wsm[k][tx];
            float w1 = Wsm[k][tx + 32];
            float w2 = Wsm[k][tx + 64];
            float w3 = Wsm[k][tx + 96];
#pragma unroll
            for (int r = 0; r < 8; ++r) {
                float a = Asm[ty * 8 + r][k];
                acc[r][0] = fmaf(a, w0, acc[r][0]);
                acc[r][1] = fmaf(a, w1, acc[r][1]);
                acc[r][2] = fmaf(a, w2, acc[r][2]);
                acc[r][3] = fmaf(a, w3, acc[r][3]);
            }
        }
        __syncthreads();
    }
    float b0 = bias[tx], b1 = bias[tx + 32], b2 = bias[tx + 64], b3 = bias[tx + 96];
#pragma unroll
    for (int r = 0; r < 8; ++r) {
        int grow = row0 + ty * 8 + r;
        if (grow < n) {
            float v0 = acc[r][0] + b0;
            float v1 = acc[r][1] + b1;
            float v2 = acc[r][2] + b2;
            float v3 = acc[r][3] + b3;
            if (relu) {
                v0 = fmaxf(v0, 0.f); v1 = fmaxf(v1, 0.f);
                v2 = fmaxf(v2, 0.f); v3 = fmaxf(v3, 0.f);
            }
            float* o = out + (size_t)grow * H;
            o[tx] = v0; o[tx + 32] = v1; o[tx + 64] = v2; o[tx + 96] = v3;
        }
    }
}

// ---------------- launch ----------------

extern "C" void kernel_launch(void* const* d_in, const int* in_sizes, int n_in,
                              void* d_out, int out_size, void* d_ws, size_t ws_size,
                              hipStream_t stream) {
    const float* x  = (const float*)d_in[0];
    const int*   ei = (const int*)d_in[1];
    const float* Wl = (const float*)d_in[2];
    const float* bl = (const float*)d_in[3];
    const float* Wr = (const float*)d_in[4];
    float* out = (float*)d_out;

    int n = in_sizes[0] / H;
    int e = in_sizes[1] / 2;
    const int* srcp = ei;
    const int* dstp = ei + e;

    char* w = (char*)d_ws;
    auto alloc = [&](size_t bytes) {
        char* p = w;
        w += (bytes + 255) & ~(size_t)255;
        return p;
    };
    int nb = (n + 1023) / 1024;
    int*   csr      = (int*)alloc((size_t)e * 4);
    int*   offsets  = (int*)alloc((size_t)(n + 1) * 4);
    int*   cursor   = (int*)alloc((size_t)n * 4);
    int*   deg      = (int*)alloc((size_t)n * 4);
    float* inv_deg  = (float*)alloc((size_t)n * 4);
    int*   partials = (int*)alloc(64 * 4);
    float* Wcat     = (float*)alloc((size_t)3 * 256 * H * 4);
    float* agg      = (float*)alloc((size_t)n * H * 4);
    float* hbuf     = (float*)alloc((size_t)n * H * 4);

    // CSR + inv_deg + Wcat (once per launch)
    k_zero_i32<<<(n + 255) / 256, 256, 0, stream>>>(deg, n);
    k_count<<<(e + 255) / 256, 256, 0, stream>>>(dstp, deg, e);
    k_scan_partial<<<nb, 1024, 0, stream>>>(deg, partials, n);
    k_scan_base<<<1, 64, 0, stream>>>(partials, nb, offsets, n);
    k_scan_final<<<nb, 1024, 0, stream>>>(deg, partials, offsets, cursor, inv_deg, n);
    k_fill<<<(e + 255) / 256, 256, 0, stream>>>(srcp, dstp, cursor, csr, e);
    int wtot = 3 * 256 * H;
    k_wcat<<<(wtot + 255) / 256, 256, 0, stream>>>(Wl, Wr, Wcat, wtot);

    const float* hin[3]  = {x, out, hbuf};
    float*       hout[3] = {out, hbuf, out};
    for (int l = 0; l < 3; ++l) {
        k_agg<<<(n + 7) / 8, 256, 0, stream>>>(hin[l], csr, offsets, inv_deg, agg, n);
        k_gemm<<<(n + 63) / 64, 256, 0, stream>>>(agg, hin[l], Wcat + (size_t)l * 256 * H,
                                                  bl + (size_t)l * H, hout[l], n, l < 2 ? 1 : 0);
    }
}